// Round 10
// baseline (118.837 us; speedup 1.0000x reference)
//
#include <hip/hip_runtime.h>
#include <hip/hip_bf16.h>

// CondLaneHead via bf16 MFMA 16x16x32, 3 layers fused. Round 10.
// 32 instances (4 img x 8), C=64, H=160, W=256, L=40960 px.
//
// r9 ledger: DS pipe is the wall (~49 DS instr/wave-inst x 160/CU x ~11cyc).
// This round cuts DS to ~33 and moves work to idle pipes:
//  - C-init via K=96 aug-MFMA (r7-proven numerics): b0/wx/wy enter layer 1
//    as hi/lo bf16 aug rows (fx,fy integer <=255 exact in bf16). -12 DS,
//    -60 VALU, +8 MFMA; baug built once per block.
//  - w1 A-frags straight from global (coalesced dwordx4, L1-shared by the
//    4 waves): -8 DS, +8 VMEM. w1 leaves the LDS double-buffer.
//  - h transform 2KB/wave nt-half reuse (r8-proven): LDS = 2x13KB dbuf +
//    8KB h = 34.8KB -> 4 blocks/CU, 16 waves/CU (vs r9's 12).
// Weight staging keeps r9's global_load_lds dbuf + 1 barrier/inst.
//
// Frag layouts (m89/m120-verified): A[m=lane&15][k=(lane>>4)*8+j],
// B[k=(lane>>4)*8+j][n=lane&15], D[row=(lane>>4)*4+r][col=lane&15].
//
// ws per instance (ISTRIDE=21504B):
//   [0,12288)     w0 A-frags K=96, frag(mt,kst)=mt*3+kst, 1KB each;
//                 kst=2 aug: k64=b0_hi k65=wx_hi k66=wx_lo k67=wy_hi
//                 k68=wy_lo k69=b0_lo k70..95=0
//   [12288,13056) vec f32: b1[64] w2[64] b2 pad to 768B   (DMA'd with w0)
//   [13312,21504) w1 A-frags, frag(mt,kst)=mt*2+kst       (read via VMEM)

#define NP 8513
#define HW 40960
#define ISTRIDE 21504
#define OFF_VEC 12288
#define OFF_W1 13312
#define DMABYTES 13312          // w0 + vec region per instance, dbuf'd in LDS

typedef __attribute__((ext_vector_type(8))) short bf16x8;
typedef __attribute__((ext_vector_type(4))) float f32x4;

__device__ inline unsigned short f2bf(float f) {
  union { float f; unsigned u; } v; v.f = f;
  unsigned r = v.u + 0x7fffu + ((v.u >> 16) & 1u);   // RNE
  return (unsigned short)(r >> 16);
}
__device__ inline float bf2f(unsigned short b) {
  union { unsigned u; float f; } v; v.u = ((unsigned)b) << 16;
  return v.f;
}
__device__ inline unsigned pk2(float a, float b) {   // [lo=a, hi=b] bf16x2
  __hip_bfloat162 h = __float22bfloat162_rn(float2{a, b});
  union { __hip_bfloat162 h; unsigned u; } v; v.h = h;
  return v.u;
}
__device__ inline void gld16(const void* g, void* l) {  // async global->LDS
  __builtin_amdgcn_global_load_lds(
      (const __attribute__((address_space(1))) unsigned*)g,
      (__attribute__((address_space(3))) unsigned*)l, 16, 0, 0);
}

__global__ void condlane_prep(const float* __restrict__ params,
                              char* __restrict__ ws) {
  const int inst = blockIdx.x >> 1, part = blockIdx.x & 1;
  const float* __restrict__ p = params + inst * NP;
  char* base = ws + inst * ISTRIDE;
  const int t = threadIdx.x;
  if (part == 0) {           // w0 A-frags incl. aug kstep (r7-proven layout)
    unsigned short* dst = (unsigned short*)base;
#pragma unroll
    for (int it = 0; it < 24; it++) {
      const int e = it * 256 + t;                    // 0..6143
      const int frag = e >> 9, lane = (e >> 3) & 63, j = e & 7;
      const int mt = frag / 3, kst = frag % 3;
      const int m = mt * 16 + (lane & 15);
      const int kl = ((lane >> 4) << 3) + j;
      unsigned short bv;
      if (kst < 2) bv = f2bf(p[m * 66 + 2 + kst * 32 + kl]);
      else if (kl == 0) bv = f2bf(p[8384 + m]);                  // b0_hi
      else if (kl == 1) bv = f2bf(p[m * 66]);                    // wx_hi
      else if (kl == 2) { float w = p[m * 66];     bv = f2bf(w - bf2f(f2bf(w))); }
      else if (kl == 3) bv = f2bf(p[m * 66 + 1]);                // wy_hi
      else if (kl == 4) { float w = p[m * 66 + 1]; bv = f2bf(w - bf2f(f2bf(w))); }
      else if (kl == 5) { float w = p[8384 + m];   bv = f2bf(w - bf2f(f2bf(w))); }
      else bv = 0;
      dst[e] = bv;
    }
    float* vec = (float*)(base + OFF_VEC);
    if (t < 64) { vec[t] = p[8448 + t]; vec[64 + t] = p[8320 + t]; }  // b1,w2
    else if (t == 64) vec[128] = p[8512] - 2.19f;                     // b2
    else if (t >= 65 && t < 128) vec[64 + t] = 0.f;                   // pad
  } else {                   // w1 A-frags
    unsigned short* dst = (unsigned short*)(base + OFF_W1);
#pragma unroll
    for (int it = 0; it < 16; it++) {
      const int e = it * 256 + t;
      const int frag = e >> 9, lane = (e >> 3) & 63, j = e & 7;
      const int m = (frag >> 1) * 16 + (lane & 15);
      const int k = (frag & 1) * 32 + ((lane >> 4) << 3) + j;
      dst[e] = f2bf(p[4224 + m * 64 + k]);
    }
  }
}

__global__ __launch_bounds__(256, 3) void condlane_main(
    const float* __restrict__ x, const char* __restrict__ ws,
    float* __restrict__ out) {
  // [0,13312) buf0, [13312,26624) buf1, [26624,34816) h (2KB/wave)
  __shared__ __align__(16) char smem[34816];
  const int img = blockIdx.y, bx = blockIdx.x;   // bx: 128-px chunk
  const int tid = threadIdx.x, lane = tid & 63, wave = tid >> 6;
  const int col = lane & 15, q = lane >> 4, sw = col & 7;
  const char* const wsb = ws + img * 8 * ISTRIDE;

  // per-wave DMA: 3 w0-units/wave; wave 3 also DMAs the 768B vec region
  auto dma = [&](int i, char* buf) {
    const char* src = wsb + i * ISTRIDE;
#pragma unroll
    for (int u = 0; u < 3; u++) {
      const int off = (wave * 3 + u) * 1024;
      gld16(src + off + lane * 16, buf + off);
    }
    if (wave == 3 && lane < 48)
      gld16(src + OFF_VEC + lane * 16, buf + OFF_VEC);
  };
  dma(0, smem);   // inst-0 weights in flight during x loads

  // ---- x B-frags straight from global to regs (reused all 8 instances) ----
  bf16x8 bfr[2][2];
  {
    const float* gx = x + img * 64 * HW + bx * 128 + wave * 32;
#pragma unroll
    for (int nt = 0; nt < 2; nt++)
#pragma unroll
      for (int ks = 0; ks < 2; ks++) {
        float f[8];
#pragma unroll
        for (int j = 0; j < 8; j++)
          f[j] = gx[(ks * 32 + q * 8 + j) * HW + nt * 16 + col];
        union { bf16x8 v; unsigned d[4]; } u;
#pragma unroll
        for (int jj = 0; jj < 4; jj++) u.d[jj] = pk2(f[2 * jj], f[2 * jj + 1]);
        bfr[nt][ks] = u.v;
      }
  }
  // aug B-frags (k=64..95): q==0 lanes hold [1, fx, fx, fy, fy, 1, 0, 0]
  bf16x8 baug[2];
  {
    const unsigned short fyb = f2bf((float)(bx >> 1));
#pragma unroll
    for (int nt = 0; nt < 2; nt++) {
      const unsigned short fxb =
          f2bf((float)((bx & 1) * 128 + wave * 32 + nt * 16 + col));
      union { bf16x8 v; unsigned short s[8]; } u;
      u.s[0] = (q == 0) ? (unsigned short)0x3F80 : (unsigned short)0;
      u.s[1] = (q == 0) ? fxb : (unsigned short)0;
      u.s[2] = u.s[1];
      u.s[3] = (q == 0) ? fyb : (unsigned short)0;
      u.s[4] = u.s[3];
      u.s[5] = u.s[0];
      u.s[6] = 0; u.s[7] = 0;
      baug[nt] = u.v;
    }
  }
  __syncthreads();   // vmcnt(0)+barrier: inst-0 DMA landed, visible to all

  unsigned short* const hwv = (unsigned short*)(smem + 26624) + wave * 1024;
  float* const outb = out + img * 8 * HW + bx * 128 + wave * 32;
  const f32x4 z4 = {0.f, 0.f, 0.f, 0.f};

  for (int i = 0; i < 8; i++) {
    char* const wb = smem + (i & 1) * DMABYTES;
    if (i < 7) dma(i + 1, smem + ((i + 1) & 1) * DMABYTES);  // async fill
    const float* const vec = (const float*)(wb + OFF_VEC);
    const char* const w1g = wsb + i * ISTRIDE + OFF_W1;      // global (L1-hot)

    // ---- layer 1: K=96 (2 x-ksteps + aug kstep), C starts at 0 ----
    f32x4 acc[4][2];
#pragma unroll
    for (int mt = 0; mt < 4; mt++) {
      const bf16x8 a0 = *(const bf16x8*)(wb + (mt * 3 + 0) * 1024 + lane * 16);
      const bf16x8 a1 = *(const bf16x8*)(wb + (mt * 3 + 1) * 1024 + lane * 16);
      const bf16x8 a2 = *(const bf16x8*)(wb + (mt * 3 + 2) * 1024 + lane * 16);
#pragma unroll
      for (int nt = 0; nt < 2; nt++) {
        f32x4 c = __builtin_amdgcn_mfma_f32_16x16x32_bf16(a0, bfr[nt][0], z4, 0, 0, 0);
        c = __builtin_amdgcn_mfma_f32_16x16x32_bf16(a1, bfr[nt][1], c, 0, 0, 0);
        acc[mt][nt] = __builtin_amdgcn_mfma_f32_16x16x32_bf16(a2, baug[nt], c, 0, 0, 0);
      }
    }
    // ---- relu -> bf16 -> swizzled LDS (2KB/wave, nt-half reuse, r8) ----
    bf16x8 hbf[2][2];
#pragma unroll
    for (int nt = 0; nt < 2; nt++) {
#pragma unroll
      for (int mt = 0; mt < 4; mt++) {
        const f32x4 v = acc[mt][nt];
        uint2 dd;
        dd.x = pk2(fmaxf(v.x, 0.f), fmaxf(v.y, 0.f));
        dd.y = pk2(fmaxf(v.z, 0.f), fmaxf(v.w, 0.f));
        const int kb = (mt * 2 + (q >> 1)) ^ sw;
        *(uint2*)(hwv + col * 64 + (kb << 3) + ((q & 1) << 2)) = dd;
      }
#pragma unroll
      for (int ks = 0; ks < 2; ks++)
        hbf[nt][ks] = *(const bf16x8*)(hwv + col * 64 + (((ks * 4 + q) ^ sw) << 3));
      // nt=1 overwrites same addrs; per-wave in-order DS keeps RAW/WAR safe
    }
    // ---- layer 2 (C=b1, w1 frags from global) + layer 3 dot fused ----
    float s0 = 0.f, s1 = 0.f;
#pragma unroll
    for (int mt = 0; mt < 4; mt++) {
      const bf16x8 a0 = *(const bf16x8*)(w1g + (mt * 2 + 0) * 1024 + lane * 16);
      const bf16x8 a1 = *(const bf16x8*)(w1g + (mt * 2 + 1) * 1024 + lane * 16);
      const int ro = mt * 16 + q * 4;
      const f32x4 cb  = *(const f32x4*)(vec + ro);        // b1 broadcast
      const f32x4 w2v = *(const f32x4*)(vec + 64 + ro);
      f32x4 c0 = __builtin_amdgcn_mfma_f32_16x16x32_bf16(a0, hbf[0][0], cb, 0, 0, 0);
      const f32x4 v0 = __builtin_amdgcn_mfma_f32_16x16x32_bf16(a1, hbf[0][1], c0, 0, 0, 0);
      f32x4 c1 = __builtin_amdgcn_mfma_f32_16x16x32_bf16(a0, hbf[1][0], cb, 0, 0, 0);
      const f32x4 v1 = __builtin_amdgcn_mfma_f32_16x16x32_bf16(a1, hbf[1][1], c1, 0, 0, 0);
      s0 += w2v.x * fmaxf(v0.x, 0.f) + w2v.y * fmaxf(v0.y, 0.f) +
            w2v.z * fmaxf(v0.z, 0.f) + w2v.w * fmaxf(v0.w, 0.f);
      s1 += w2v.x * fmaxf(v1.x, 0.f) + w2v.y * fmaxf(v1.y, 0.f) +
            w2v.z * fmaxf(v1.z, 0.f) + w2v.w * fmaxf(v1.w, 0.f);
    }
    const float b2i = vec[128];
    s0 += __shfl_xor(s0, 16, 64); s0 += __shfl_xor(s0, 32, 64);
    s1 += __shfl_xor(s1, 16, 64); s1 += __shfl_xor(s1, 32, 64);
    if (lane < 32)
      outb[i * HW + q * 16 + col] = (q ? s1 : s0) + b2i;

    // barrier: drains DMA (vmcnt0) so next buf is ready; also gates WAR
    if (i < 7) __syncthreads();
  }
}

extern "C" void kernel_launch(void* const* d_in, const int* in_sizes, int n_in,
                              void* d_out, int out_size, void* d_ws, size_t ws_size,
                              hipStream_t stream) {
  const float* x      = (const float*)d_in[0];  // [4,64,160,256] fp32
  const float* params = (const float*)d_in[1];  // [32,8513] fp32
  // d_in[2] = num_ins (static 8/img; inst mapping hardcoded)
  float* out = (float*)d_out;

  condlane_prep<<<64, 256, 0, stream>>>(params, (char*)d_ws);   // 688 KB used
  condlane_main<<<dim3(320, 4), 256, 0, stream>>>(x, (const char*)d_ws, out);
}

// Round 11
// 114.719 us; speedup vs baseline: 1.0359x; 1.0359x over previous
//
#include <hip/hip_runtime.h>
#include <hip/hip_bf16.h>

// CondLaneHead via bf16 MFMA 16x16x32, 3 layers fused. Round 11.
// 32 instances (4 img x 8), C=64, H=160, W=256, L=40960 px.
//
// r10 ledger: VALUBusy 49% was 5x the hand-counted arithmetic -> hidden hog
// = software RNE bf16 packing (~6 ops/elem). gfx950 has single-instruction
// v_cvt_pk_bf16_f32 (RNE, CDNA3+) -> inline asm. Prep now stages params in
// LDS (coalesced global reads). Structure otherwise identical to r10:
//  - layer1 K=96 aug-MFMA (b0/wx/wy as hi/lo bf16 rows, fx/fy exact)
//  - w0+vec via global_load_lds double-buffer, 1 barrier/inst
//  - w1 A-frags straight from global (L1-shared across waves)
//  - h transform: swizzled 2KB/wave LDS round-trip, nt-half reuse
//
// Frag layouts (m89/m120-verified): A[m=lane&15][k=(lane>>4)*8+j],
// B[k=(lane>>4)*8+j][n=lane&15], D[row=(lane>>4)*4+r][col=lane&15].
//
// ws per instance (ISTRIDE=21504B):
//   [0,12288)     w0 A-frags K=96, frag(mt,kst)=mt*3+kst, 1KB each;
//                 kst=2 aug: k64=b0_hi k65=wx_hi k66=wx_lo k67=wy_hi
//                 k68=wy_lo k69=b0_lo k70..95=0
//   [12288,13056) vec f32: b1[64] w2[64] b2 pad to 768B   (DMA'd with w0)
//   [13312,21504) w1 A-frags, frag(mt,kst)=mt*2+kst       (read via VMEM)

#define NP 8513
#define HW 40960
#define ISTRIDE 21504
#define OFF_VEC 12288
#define OFF_W1 13312
#define DMABYTES 13312          // w0 + vec region per instance, dbuf'd in LDS

typedef __attribute__((ext_vector_type(8))) short bf16x8;
typedef __attribute__((ext_vector_type(4))) float f32x4;

__device__ inline unsigned short f2bf(float f) {     // cold paths only
  union { float f; unsigned u; } v; v.f = f;
  unsigned r = v.u + 0x7fffu + ((v.u >> 16) & 1u);   // RNE
  return (unsigned short)(r >> 16);
}
__device__ inline float bf2f(unsigned short b) {
  union { unsigned u; float f; } v; v.u = ((unsigned)b) << 16;
  return v.f;
}
// single-instruction RNE pack: D[15:0]=bf16(a), D[31:16]=bf16(b)
__device__ inline unsigned pk2(float a, float b) {
  unsigned r;
  asm("v_cvt_pk_bf16_f32 %0, %1, %2" : "=v"(r) : "v"(a), "v"(b));
  return r;
}
__device__ inline void gld16(const void* g, void* l) {  // async global->LDS
  __builtin_amdgcn_global_load_lds(
      (const __attribute__((address_space(1))) unsigned*)g,
      (__attribute__((address_space(3))) unsigned*)l, 16, 0, 0);
}

// one block per instance; params staged in LDS so global reads are coalesced
__global__ void condlane_prep(const float* __restrict__ params,
                              char* __restrict__ ws) {
  __shared__ float pl[NP];
  const int inst = blockIdx.x;
  const float* __restrict__ p = params + inst * NP;
  char* base = ws + inst * ISTRIDE;
  const int t = threadIdx.x;
  for (int e = t; e < NP; e += 256) pl[e] = p[e];   // fully coalesced
  __syncthreads();

  unsigned short* w0d = (unsigned short*)base;
#pragma unroll
  for (int it = 0; it < 24; it++) {                 // w0 A-frags K=96 + aug
    const int e = it * 256 + t;                     // 0..6143
    const int frag = e >> 9, lane = (e >> 3) & 63, j = e & 7;
    const int mt = frag / 3, kst = frag % 3;
    const int m = mt * 16 + (lane & 15);
    const int kl = ((lane >> 4) << 3) + j;
    unsigned short bv;
    if (kst < 2) bv = f2bf(pl[m * 66 + 2 + kst * 32 + kl]);
    else if (kl == 0) bv = f2bf(pl[8384 + m]);                  // b0_hi
    else if (kl == 1) bv = f2bf(pl[m * 66]);                    // wx_hi
    else if (kl == 2) { float w = pl[m * 66];     bv = f2bf(w - bf2f(f2bf(w))); }
    else if (kl == 3) bv = f2bf(pl[m * 66 + 1]);                // wy_hi
    else if (kl == 4) { float w = pl[m * 66 + 1]; bv = f2bf(w - bf2f(f2bf(w))); }
    else if (kl == 5) { float w = pl[8384 + m];   bv = f2bf(w - bf2f(f2bf(w))); }
    else bv = 0;
    w0d[e] = bv;
  }
  unsigned short* w1d = (unsigned short*)(base + OFF_W1);
#pragma unroll
  for (int it = 0; it < 16; it++) {                 // w1 A-frags
    const int e = it * 256 + t;
    const int frag = e >> 9, lane = (e >> 3) & 63, j = e & 7;
    const int m = (frag >> 1) * 16 + (lane & 15);
    const int k = (frag & 1) * 32 + ((lane >> 4) << 3) + j;
    w1d[e] = f2bf(pl[4224 + m * 64 + k]);
  }
  float* vec = (float*)(base + OFF_VEC);
  if (t < 64) { vec[t] = pl[8448 + t]; vec[64 + t] = pl[8320 + t]; }  // b1,w2
  else if (t == 64) vec[128] = pl[8512] - 2.19f;                      // b2
  else if (t >= 65 && t < 128) vec[64 + t] = 0.f;                     // pad
}

__global__ __launch_bounds__(256, 3) void condlane_main(
    const float* __restrict__ x, const char* __restrict__ ws,
    float* __restrict__ out) {
  // [0,13312) buf0, [13312,26624) buf1, [26624,34816) h (2KB/wave)
  __shared__ __align__(16) char smem[34816];
  const int img = blockIdx.y, bx = blockIdx.x;   // bx: 128-px chunk
  const int tid = threadIdx.x, lane = tid & 63, wave = tid >> 6;
  const int col = lane & 15, q = lane >> 4, sw = col & 7;
  const char* const wsb = ws + img * 8 * ISTRIDE;

  // per-wave DMA: 3 w0-units/wave; wave 3 also DMAs the 768B vec region
  auto dma = [&](int i, char* buf) {
    const char* src = wsb + i * ISTRIDE;
#pragma unroll
    for (int u = 0; u < 3; u++) {
      const int off = (wave * 3 + u) * 1024;
      gld16(src + off + lane * 16, buf + off);
    }
    if (wave == 3 && lane < 48)
      gld16(src + OFF_VEC + lane * 16, buf + OFF_VEC);
  };
  dma(0, smem);   // inst-0 weights in flight during x loads

  // ---- x B-frags straight from global to regs (reused all 8 instances) ----
  bf16x8 bfr[2][2];
  {
    const float* gx = x + img * 64 * HW + bx * 128 + wave * 32;
#pragma unroll
    for (int nt = 0; nt < 2; nt++)
#pragma unroll
      for (int ks = 0; ks < 2; ks++) {
        float f[8];
#pragma unroll
        for (int j = 0; j < 8; j++)
          f[j] = gx[(ks * 32 + q * 8 + j) * HW + nt * 16 + col];
        union { bf16x8 v; unsigned d[4]; } u;
#pragma unroll
        for (int jj = 0; jj < 4; jj++) u.d[jj] = pk2(f[2 * jj], f[2 * jj + 1]);
        bfr[nt][ks] = u.v;
      }
  }
  // aug B-frags (k=64..95): q==0 lanes hold [1, fx, fx, fy, fy, 1, 0, 0]
  bf16x8 baug[2];
  {
    const unsigned short fyb = f2bf((float)(bx >> 1));
#pragma unroll
    for (int nt = 0; nt < 2; nt++) {
      const unsigned short fxb =
          f2bf((float)((bx & 1) * 128 + wave * 32 + nt * 16 + col));
      union { bf16x8 v; unsigned short s[8]; } u;
      u.s[0] = (q == 0) ? (unsigned short)0x3F80 : (unsigned short)0;
      u.s[1] = (q == 0) ? fxb : (unsigned short)0;
      u.s[2] = u.s[1];
      u.s[3] = (q == 0) ? fyb : (unsigned short)0;
      u.s[4] = u.s[3];
      u.s[5] = u.s[0];
      u.s[6] = 0; u.s[7] = 0;
      baug[nt] = u.v;
    }
  }
  __syncthreads();   // vmcnt(0)+barrier: inst-0 DMA landed, visible to all

  unsigned short* const hwv = (unsigned short*)(smem + 26624) + wave * 1024;
  float* const outb = out + img * 8 * HW + bx * 128 + wave * 32;
  const f32x4 z4 = {0.f, 0.f, 0.f, 0.f};

  for (int i = 0; i < 8; i++) {
    char* const wb = smem + (i & 1) * DMABYTES;
    if (i < 7) dma(i + 1, smem + ((i + 1) & 1) * DMABYTES);  // async fill
    const float* const vec = (const float*)(wb + OFF_VEC);
    const char* const w1g = wsb + i * ISTRIDE + OFF_W1;      // global (L1-hot)

    // ---- layer 1: K=96 (2 x-ksteps + aug kstep), C starts at 0 ----
    f32x4 acc[4][2];
#pragma unroll
    for (int mt = 0; mt < 4; mt++) {
      const bf16x8 a0 = *(const bf16x8*)(wb + (mt * 3 + 0) * 1024 + lane * 16);
      const bf16x8 a1 = *(const bf16x8*)(wb + (mt * 3 + 1) * 1024 + lane * 16);
      const bf16x8 a2 = *(const bf16x8*)(wb + (mt * 3 + 2) * 1024 + lane * 16);
#pragma unroll
      for (int nt = 0; nt < 2; nt++) {
        f32x4 c = __builtin_amdgcn_mfma_f32_16x16x32_bf16(a0, bfr[nt][0], z4, 0, 0, 0);
        c = __builtin_amdgcn_mfma_f32_16x16x32_bf16(a1, bfr[nt][1], c, 0, 0, 0);
        acc[mt][nt] = __builtin_amdgcn_mfma_f32_16x16x32_bf16(a2, baug[nt], c, 0, 0, 0);
      }
    }
    // ---- relu -> v_cvt_pk_bf16 -> swizzled LDS (2KB/wave, nt-half reuse) ----
    bf16x8 hbf[2][2];
#pragma unroll
    for (int nt = 0; nt < 2; nt++) {
#pragma unroll
      for (int mt = 0; mt < 4; mt++) {
        const f32x4 v = acc[mt][nt];
        uint2 dd;
        dd.x = pk2(fmaxf(v.x, 0.f), fmaxf(v.y, 0.f));
        dd.y = pk2(fmaxf(v.z, 0.f), fmaxf(v.w, 0.f));
        const int kb = (mt * 2 + (q >> 1)) ^ sw;
        *(uint2*)(hwv + col * 64 + (kb << 3) + ((q & 1) << 2)) = dd;
      }
#pragma unroll
      for (int ks = 0; ks < 2; ks++)
        hbf[nt][ks] = *(const bf16x8*)(hwv + col * 64 + (((ks * 4 + q) ^ sw) << 3));
      // nt=1 overwrites same addrs; per-wave in-order DS keeps RAW/WAR safe
    }
    // ---- layer 2 (C=b1, w1 frags from global) + layer 3 dot fused ----
    float s0 = 0.f, s1 = 0.f;
#pragma unroll
    for (int mt = 0; mt < 4; mt++) {
      const bf16x8 a0 = *(const bf16x8*)(w1g + (mt * 2 + 0) * 1024 + lane * 16);
      const bf16x8 a1 = *(const bf16x8*)(w1g + (mt * 2 + 1) * 1024 + lane * 16);
      const int ro = mt * 16 + q * 4;
      const f32x4 cb  = *(const f32x4*)(vec + ro);        // b1 broadcast
      const f32x4 w2v = *(const f32x4*)(vec + 64 + ro);
      f32x4 c0 = __builtin_amdgcn_mfma_f32_16x16x32_bf16(a0, hbf[0][0], cb, 0, 0, 0);
      const f32x4 v0 = __builtin_amdgcn_mfma_f32_16x16x32_bf16(a1, hbf[0][1], c0, 0, 0, 0);
      f32x4 c1 = __builtin_amdgcn_mfma_f32_16x16x32_bf16(a0, hbf[1][0], cb, 0, 0, 0);
      const f32x4 v1 = __builtin_amdgcn_mfma_f32_16x16x32_bf16(a1, hbf[1][1], c1, 0, 0, 0);
      s0 += w2v.x * fmaxf(v0.x, 0.f) + w2v.y * fmaxf(v0.y, 0.f) +
            w2v.z * fmaxf(v0.z, 0.f) + w2v.w * fmaxf(v0.w, 0.f);
      s1 += w2v.x * fmaxf(v1.x, 0.f) + w2v.y * fmaxf(v1.y, 0.f) +
            w2v.z * fmaxf(v1.z, 0.f) + w2v.w * fmaxf(v1.w, 0.f);
    }
    const float b2i = vec[128];
    s0 += __shfl_xor(s0, 16, 64); s0 += __shfl_xor(s0, 32, 64);
    s1 += __shfl_xor(s1, 16, 64); s1 += __shfl_xor(s1, 32, 64);
    if (lane < 32)
      outb[i * HW + q * 16 + col] = (q ? s1 : s0) + b2i;

    // barrier: drains DMA (vmcnt0) so next buf is ready; also gates WAR
    if (i < 7) __syncthreads();
  }
}

extern "C" void kernel_launch(void* const* d_in, const int* in_sizes, int n_in,
                              void* d_out, int out_size, void* d_ws, size_t ws_size,
                              hipStream_t stream) {
  const float* x      = (const float*)d_in[0];  // [4,64,160,256] fp32
  const float* params = (const float*)d_in[1];  // [32,8513] fp32
  // d_in[2] = num_ins (static 8/img; inst mapping hardcoded)
  float* out = (float*)d_out;

  condlane_prep<<<32, 256, 0, stream>>>(params, (char*)d_ws);   // 688 KB used
  condlane_main<<<dim3(320, 4), 256, 0, stream>>>(x, (const char*)d_ws, out);
}